// Round 1
// baseline (3686.691 us; speedup 1.0000x reference)
//
#include <hip/hip_runtime.h>
#include <math.h>

#define N_WIN 2048
#define PW    64
#define KA    40            // active tokens per window (K - PAD)
#define MSEL  1536
#define BSZ   8
#define CH    128
#define DH    32
#define NH    4
#define GLUI  320           // INNER
#define WIN_PER_CHUNK (N_WIN / BSZ)         // 256
#define ROWS_PER_CHUNK ((N_WIN / BSZ) * PW) // 16384

// ---------------- K1: LayerNorm1 over every (N*P) row, write to d_out -------
__global__ __launch_bounds__(256) void k_ln1(const float* __restrict__ x,
                                             const float* __restrict__ g,
                                             const float* __restrict__ b,
                                             float* __restrict__ out) {
    int wave = threadIdx.x >> 6;
    int lane = threadIdx.x & 63;
    long row = (long)blockIdx.x * 4 + wave;          // 131072 rows total
    const float* xr = x + row * CH;
    float2 v = *(const float2*)(xr + lane * 2);
    float s  = v.x + v.y;
    float s2 = v.x * v.x + v.y * v.y;
    #pragma unroll
    for (int off = 32; off; off >>= 1) { s += __shfl_xor(s, off); s2 += __shfl_xor(s2, off); }
    float mu  = s * (1.f / CH);
    float var = s2 * (1.f / CH) - mu * mu;
    float r   = rsqrtf(var + 1e-5f);
    float2 o;
    o.x = (v.x - mu) * r * g[lane * 2]     + b[lane * 2];
    o.y = (v.y - mu) * r * g[lane * 2 + 1] + b[lane * 2 + 1];
    *(float2*)(out + row * CH + lane * 2) = o;
}

// ---------------- K2: per-window LN2 + QKV + attention + proj + residual ----
__global__ __launch_bounds__(256) void k_attn(const float* __restrict__ ln1,
                                              const float* __restrict__ n2g,
                                              const float* __restrict__ n2b,
                                              const float* __restrict__ qkv_w,
                                              const float* __restrict__ qkv_b,
                                              const float* __restrict__ proj_w,
                                              const float* __restrict__ proj_b,
                                              const float* __restrict__ ls1,
                                              const int*   __restrict__ iw,
                                              float* __restrict__ r1out) {
    __shared__ float s1[KA][CH];       // 20.5 KB  (LN2 output, kept for residual)
    __shared__ float qkv[KA][384];     // 61.4 KB  (q|k|v per head; o overwrites q slot)
    __shared__ float sc[KA][KA];       // 6.4 KB   (scores, per head)
    int m = blockIdx.x;
    int w = iw[m];
    const float* base = ln1 + ((long)w * PW) * CH;
    int wave = threadIdx.x >> 6, lane = threadIdx.x & 63;

    // LN2 on the 40 active rows (inputs are LN1 rows already in d_out)
    for (int r = wave; r < KA; r += 4) {
        float2 v = *(const float2*)(base + r * CH + lane * 2);
        float s = v.x + v.y, s2 = v.x * v.x + v.y * v.y;
        #pragma unroll
        for (int off = 32; off; off >>= 1) { s += __shfl_xor(s, off); s2 += __shfl_xor(s2, off); }
        float mu = s * (1.f / CH);
        float var = s2 * (1.f / CH) - mu * mu;
        float rr = rsqrtf(var + 1e-5f);
        s1[r][lane * 2]     = (v.x - mu) * rr * n2g[lane * 2]     + n2b[lane * 2];
        s1[r][lane * 2 + 1] = (v.y - mu) * rr * n2g[lane * 2 + 1] + n2b[lane * 2 + 1];
    }
    __syncthreads();

    // QKV GEMM: (40x128) @ (128x384) + b  ; col layout per head h: [q(32)|k(32)|v(32)]
    for (int idx = threadIdx.x; idx < KA * 384; idx += 256) {
        int r = idx / 384, col = idx % 384;
        float acc = qkv_b[col];
        #pragma unroll 4
        for (int c = 0; c < CH; ++c) acc += s1[r][c] * qkv_w[c * 384 + col];
        qkv[r][col] = acc;
    }
    __syncthreads();

    const float scale = 0.17677669529663687f;  // 1/sqrt(32)
    for (int h = 0; h < NH; ++h) {
        const int qo = h * 96, ko = h * 96 + 32, vo = h * 96 + 64;
        for (int idx = threadIdx.x; idx < KA * KA; idx += 256) {
            int i = idx / KA, j = idx % KA;
            float acc = 0.f;
            #pragma unroll
            for (int d = 0; d < DH; ++d) acc += qkv[i][qo + d] * qkv[j][ko + d];
            sc[i][j] = acc * scale;
        }
        __syncthreads();
        if (threadIdx.x < KA) {      // row softmax; masked keys (>=40) omitted entirely
            int i = threadIdx.x;
            float mx = -1e30f;
            for (int j = 0; j < KA; ++j) mx = fmaxf(mx, sc[i][j]);
            float ss = 0.f;
            for (int j = 0; j < KA; ++j) { float e = expf(sc[i][j] - mx); sc[i][j] = e; ss += e; }
            float inv = 1.f / ss;
            for (int j = 0; j < KA; ++j) sc[i][j] *= inv;
        }
        __syncthreads();
        // o_head = P @ V  -> write into q slot of this head (q no longer needed)
        for (int idx = threadIdx.x; idx < KA * DH; idx += 256) {
            int i = idx / DH, d = idx % DH;
            float acc = 0.f;
            #pragma unroll 4
            for (int j = 0; j < KA; ++j) acc += sc[i][j] * qkv[j][vo + d];
            qkv[i][qo + d] = acc;    // safe: scores for head h already consumed from k slot
        }
        __syncthreads();
    }

    // proj: o(40x128) @ proj_w(128x128) + b ; residual r1 = s1 + o_proj*ls1
    for (int idx = threadIdx.x; idx < KA * CH; idx += 256) {
        int i = idx / CH, c = idx % CH;
        float acc = proj_b[c];
        #pragma unroll 4
        for (int cc = 0; cc < CH; ++cc) {
            acc += qkv[i][(cc / DH) * 96 + (cc % DH)] * proj_w[cc * CH + c];
        }
        float v = s1[i][c] + acc * ls1[c];
        r1out[((long)m * KA + i) * CH + c] = v;
    }
}

// ---------------- K3: per-window LN2 + GLU-MLP + chunk-sum accumulation -----
__global__ __launch_bounds__(256) void k_mlp(const float* __restrict__ r1,
                                             const float* __restrict__ n2g,
                                             const float* __restrict__ n2b,
                                             const float* __restrict__ glu_w,
                                             const float* __restrict__ glu_b,
                                             const float* __restrict__ out_w,
                                             const float* __restrict__ out_b,
                                             const int*   __restrict__ iw,
                                             float* __restrict__ mlpout,
                                             float* __restrict__ chunksum) {
    __shared__ float h[KA][CH];        // 20.5 KB
    __shared__ float a[KA][GLUI];      // 51.2 KB
    __shared__ float bsum[CH];
    int m = blockIdx.x;
    int wave = threadIdx.x >> 6, lane = threadIdx.x & 63;

    for (int r = wave; r < KA; r += 4) {
        float2 v = *(const float2*)(r1 + ((long)m * KA + r) * CH + lane * 2);
        float s = v.x + v.y, s2 = v.x * v.x + v.y * v.y;
        #pragma unroll
        for (int off = 32; off; off >>= 1) { s += __shfl_xor(s, off); s2 += __shfl_xor(s2, off); }
        float mu = s * (1.f / CH);
        float var = s2 * (1.f / CH) - mu * mu;
        float rr = rsqrtf(var + 1e-5f);
        h[r][lane * 2]     = (v.x - mu) * rr * n2g[lane * 2]     + n2b[lane * 2];
        h[r][lane * 2 + 1] = (v.y - mu) * rr * n2g[lane * 2 + 1] + n2b[lane * 2 + 1];
    }
    if (threadIdx.x < CH) bsum[threadIdx.x] = 0.f;
    __syncthreads();

    // GLU: [u|g] = h @ glu_w + glu_b ; a = u * gelu_exact(g)
    for (int idx = threadIdx.x; idx < KA * GLUI; idx += 256) {
        int r = idx / GLUI, j = idx % GLUI;
        float u = glu_b[j], g = glu_b[j + GLUI];
        #pragma unroll 4
        for (int c = 0; c < CH; ++c) {
            float hv = h[r][c];
            u += hv * glu_w[c * (2 * GLUI) + j];
            g += hv * glu_w[c * (2 * GLUI) + j + GLUI];
        }
        float ge = 0.5f * g * (1.f + erff(g * 0.70710678118654752f));
        a[r][j] = u * ge;
    }
    __syncthreads();

    // out proj: (40x320) @ (320x128) + b ; also block-sum for CB chunk means
    for (int idx = threadIdx.x; idx < KA * CH; idx += 256) {
        int r = idx / CH, c = idx % CH;
        float acc = out_b[c];
        #pragma unroll 4
        for (int j = 0; j < GLUI; ++j) acc += a[r][j] * out_w[j * CH + c];
        mlpout[((long)m * KA + r) * CH + c] = acc;
        atomicAdd(&bsum[c], acc);
    }
    __syncthreads();
    if (threadIdx.x < CH) {
        int cid = iw[m] / WIN_PER_CHUNK;
        atomicAdd(&chunksum[cid * CH + threadIdx.x], bsum[threadIdx.x]);
    }
}

// ---------------- K4: finalize + scatter into d_out -------------------------
__global__ __launch_bounds__(256) void k_final(const float* __restrict__ r1,
                                               const float* __restrict__ mlpout,
                                               const float* __restrict__ chunksum,
                                               const float* __restrict__ ls2,
                                               const int*   __restrict__ iw,
                                               const int*   __restrict__ ecb,
                                               float* __restrict__ out) {
    long idx = (long)blockIdx.x * 256 + threadIdx.x;   // exactly MSEL*KA*CH threads
    int c = (int)(idx % CH);
    long row = idx / CH;
    int m = (int)(row / KA);
    int k = (int)(row % KA);
    int w = iw[m];
    float xa = mlpout[idx];
    if (ecb[0]) {
        int cid = w / WIN_PER_CHUNK;
        xa = 0.5f * xa + (0.5f / ROWS_PER_CHUNK) * chunksum[cid * CH + c];
    }
    out[((long)(w * PW + k)) * CH + c] = r1[idx] + xa * ls2[c];
}

extern "C" void kernel_launch(void* const* d_in, const int* in_sizes, int n_in,
                              void* d_out, int out_size, void* d_ws, size_t ws_size,
                              hipStream_t stream) {
    const float* x      = (const float*)d_in[0];
    const float* n1g    = (const float*)d_in[1];
    const float* n1b    = (const float*)d_in[2];
    const float* n2g    = (const float*)d_in[3];
    const float* n2b    = (const float*)d_in[4];
    const float* qkv_w  = (const float*)d_in[5];
    const float* qkv_b  = (const float*)d_in[6];
    const float* proj_w = (const float*)d_in[7];
    const float* proj_b = (const float*)d_in[8];
    const float* ls1    = (const float*)d_in[9];
    const float* ls2    = (const float*)d_in[10];
    const float* glu_w  = (const float*)d_in[11];
    const float* glu_b  = (const float*)d_in[12];
    const float* out_w  = (const float*)d_in[13];
    const float* out_b  = (const float*)d_in[14];
    const int*   iw     = (const int*)d_in[15];
    const int*   ecb    = (const int*)d_in[21];
    float* out = (float*)d_out;

    float* r1   = (float*)d_ws;                         // 61440*128 f32 = 31.5 MB
    float* mlp  = r1 + (long)MSEL * KA * CH;            // 31.5 MB
    float* csum = mlp + (long)MSEL * KA * CH;           // 8*128 f32

    hipMemsetAsync(csum, 0, BSZ * CH * sizeof(float), stream);
    k_ln1 <<<N_WIN * PW / 4, 256, 0, stream>>>(x, n1g, n1b, out);
    k_attn<<<MSEL, 256, 0, stream>>>(out, n2g, n2b, qkv_w, qkv_b, proj_w, proj_b, ls1, iw, r1);
    k_mlp <<<MSEL, 256, 0, stream>>>(r1, n2g, n2b, glu_w, glu_b, out_w, out_b, iw, mlp, csum);
    k_final<<<(MSEL * KA * CH) / 256, 256, 0, stream>>>(r1, mlp, csum, ls2, iw, ecb, out);
    (void)in_sizes; (void)n_in; (void)out_size; (void)ws_size;
}

// Round 2
// 278.070 us; speedup vs baseline: 13.2581x; 13.2581x over previous
//
#include <hip/hip_runtime.h>
#include <math.h>

typedef unsigned short u16;
typedef unsigned int   u32;
typedef __attribute__((ext_vector_type(8))) short bf16x8;
typedef __attribute__((ext_vector_type(4))) float f32x4;

#define N_WIN 2048
#define PW    64
#define KA    40
#define MSEL  1536
#define CH    128
#define NH    4
#define GLUI  320
#define NTOK  (MSEL*KA)          // 61440
#define WPC   256                // windows per chunk
#define RPC   16384              // rows per chunk (for CB mean)

__device__ __forceinline__ u16 f2b(float f) {
    u32 u = __float_as_uint(f);
    return (u16)((u + 0x7FFFu + ((u >> 16) & 1u)) >> 16);
}
__device__ __forceinline__ float b2f(u16 v) { return __uint_as_float(((u32)v) << 16); }

// ---------------- weight fp32 -> bf16 transposed: Wt[n][k] = W[k][n] --------
__global__ __launch_bounds__(256) void k_cvtT(const float* __restrict__ W,
                                              u16* __restrict__ Wt, int K, int N) {
    int idx = blockIdx.x * 256 + threadIdx.x;
    if (idx >= K * N) return;
    int n = idx / K, k = idx % K;
    Wt[idx] = f2b(W[k * N + n]);
}

// ---------------- LN1 over all 131072 rows -> d_out -------------------------
__global__ __launch_bounds__(256) void k_ln1(const float* __restrict__ x,
                                             const float* __restrict__ g,
                                             const float* __restrict__ b,
                                             float* __restrict__ out) {
    int wave = threadIdx.x >> 6, lane = threadIdx.x & 63;
    long row = (long)blockIdx.x * 4 + wave;
    float2 v = *(const float2*)(x + row * CH + lane * 2);
    float s = v.x + v.y, s2 = v.x * v.x + v.y * v.y;
    #pragma unroll
    for (int o = 32; o; o >>= 1) { s += __shfl_xor(s, o); s2 += __shfl_xor(s2, o); }
    float mu = s * (1.f / CH), var = s2 * (1.f / CH) - mu * mu;
    float r = rsqrtf(var + 1e-5f);
    float2 o;
    o.x = (v.x - mu) * r * g[lane * 2]     + b[lane * 2];
    o.y = (v.y - mu) * r * g[lane * 2 + 1] + b[lane * 2 + 1];
    *(float2*)(out + row * CH + lane * 2) = o;
}

// ---------------- gather + LN2 -> s1 fp32 (residual) + bf16 (GEMM A) --------
__global__ __launch_bounds__(256) void k_ln2a(const float* __restrict__ ln1,
                                              const float* __restrict__ g2,
                                              const float* __restrict__ b2,
                                              const int* __restrict__ iw,
                                              float* __restrict__ s1f,
                                              u16* __restrict__ s1h) {
    int wave = threadIdx.x >> 6, lane = threadIdx.x & 63;
    long row = (long)blockIdx.x * 4 + wave;          // < 61440
    int m = (int)(row / KA), r = (int)(row % KA);
    const float* src = ln1 + ((long)iw[m] * PW + r) * CH;
    float2 v = *(const float2*)(src + lane * 2);
    float s = v.x + v.y, s2 = v.x * v.x + v.y * v.y;
    #pragma unroll
    for (int o = 32; o; o >>= 1) { s += __shfl_xor(s, o); s2 += __shfl_xor(s2, o); }
    float mu = s * (1.f / CH), var = s2 * (1.f / CH) - mu * mu;
    float rr = rsqrtf(var + 1e-5f);
    float o0 = (v.x - mu) * rr * g2[lane * 2]     + b2[lane * 2];
    float o1 = (v.y - mu) * rr * g2[lane * 2 + 1] + b2[lane * 2 + 1];
    float2 of; of.x = o0; of.y = o1;
    *(float2*)(s1f + row * CH + lane * 2) = of;
    *(u32*)(s1h + row * CH + lane * 2) = (u32)f2b(o0) | ((u32)f2b(o1) << 16);
}

// ---------------- LN2 of r1 -> h bf16 ---------------------------------------
__global__ __launch_bounds__(256) void k_ln2b(const float* __restrict__ r1,
                                              const float* __restrict__ g2,
                                              const float* __restrict__ b2,
                                              u16* __restrict__ hh) {
    int wave = threadIdx.x >> 6, lane = threadIdx.x & 63;
    long row = (long)blockIdx.x * 4 + wave;
    float2 v = *(const float2*)(r1 + row * CH + lane * 2);
    float s = v.x + v.y, s2 = v.x * v.x + v.y * v.y;
    #pragma unroll
    for (int o = 32; o; o >>= 1) { s += __shfl_xor(s, o); s2 += __shfl_xor(s2, o); }
    float mu = s * (1.f / CH), var = s2 * (1.f / CH) - mu * mu;
    float rr = rsqrtf(var + 1e-5f);
    float o0 = (v.x - mu) * rr * g2[lane * 2]     + b2[lane * 2];
    float o1 = (v.y - mu) * rr * g2[lane * 2 + 1] + b2[lane * 2 + 1];
    *(u32*)(hh + row * CH + lane * 2) = (u32)f2b(o0) | ((u32)f2b(o1) << 16);
}

// ---------------- tiled MFMA GEMM: C = A(bf16, NTOKxKT) @ Bt^T + epi --------
// EPI 0: outh = bf16(C + bias)            (QKV, ldo = 384)
// EPI 1: outf = s1f + (C + bias) * ls1    (PROJ, stride 128)
// EPI 2: outf = C + bias                  (OUT,  stride 128)
template<int KT, int EPI>
__global__ __launch_bounds__(256) void k_gemm(const u16* __restrict__ A,
                                              const u16* __restrict__ Bt,
                                              const float* __restrict__ bias,
                                              const float* __restrict__ s1f,
                                              const float* __restrict__ ls1,
                                              float* __restrict__ outf,
                                              u16* __restrict__ outh, int ldo) {
    __shared__ u16 Al[128][72];
    __shared__ u16 Bl[64][72];
    int tid = threadIdx.x, wid = tid >> 6, lane = tid & 63;
    int l15 = lane & 15, lg = lane >> 4;
    long m0 = (long)blockIdx.x * 128;
    int n0 = blockIdx.y * 64;
    f32x4 acc[2][4] = {};
    for (int kc = 0; kc < KT; kc += 64) {
        #pragma unroll
        for (int ch = 0; ch < 4; ++ch) {
            int id = tid + ch * 256; int r = id >> 3, cs = id & 7;
            *(bf16x8*)&Al[r][cs * 8] = *(const bf16x8*)&A[(m0 + r) * KT + kc + cs * 8];
        }
        #pragma unroll
        for (int ch = 0; ch < 2; ++ch) {
            int id = tid + ch * 256; int r = id >> 3, cs = id & 7;
            *(bf16x8*)&Bl[r][cs * 8] = *(const bf16x8*)&Bt[(long)(n0 + r) * KT + kc + cs * 8];
        }
        __syncthreads();
        #pragma unroll
        for (int ks = 0; ks < 2; ++ks) {
            bf16x8 af[2], bfr[4];
            #pragma unroll
            for (int i = 0; i < 2; ++i) af[i] = *(const bf16x8*)&Al[wid * 32 + i * 16 + l15][ks * 32 + lg * 8];
            #pragma unroll
            for (int j = 0; j < 4; ++j) bfr[j] = *(const bf16x8*)&Bl[j * 16 + l15][ks * 32 + lg * 8];
            #pragma unroll
            for (int i = 0; i < 2; ++i)
                #pragma unroll
                for (int j = 0; j < 4; ++j)
                    acc[i][j] = __builtin_amdgcn_mfma_f32_16x16x32_bf16(af[i], bfr[j], acc[i][j], 0, 0, 0);
        }
        __syncthreads();
    }
    #pragma unroll
    for (int i = 0; i < 2; ++i)
        #pragma unroll
        for (int j = 0; j < 4; ++j) {
            int col = n0 + j * 16 + l15;
            float bcol = bias[col];
            #pragma unroll
            for (int r = 0; r < 4; ++r) {
                long row = m0 + wid * 32 + i * 16 + lg * 4 + r;
                float v = acc[i][j][r] + bcol;
                if (EPI == 0)      outh[row * ldo + col] = f2b(v);
                else if (EPI == 1) outf[row * CH + col]  = s1f[row * CH + col] + v * ls1[col];
                else               outf[row * CH + col]  = v;
            }
        }
}

// ---------------- GLU GEMM: act = (u+bu) * gelu(g+bg), dual B tiles ---------
__global__ __launch_bounds__(256) void k_gemm_glu(const u16* __restrict__ A,
                                                  const u16* __restrict__ Wt,
                                                  const float* __restrict__ gb,
                                                  u16* __restrict__ act) {
    __shared__ u16 Al[128][72];
    __shared__ u16 Bu[64][72];
    __shared__ u16 Bg[64][72];
    int tid = threadIdx.x, wid = tid >> 6, lane = tid & 63;
    int l15 = lane & 15, lg = lane >> 4;
    long m0 = (long)blockIdx.x * 128;
    int n0 = blockIdx.y * 64;
    f32x4 au[2][4] = {}, ag[2][4] = {};
    for (int kc = 0; kc < CH; kc += 64) {
        #pragma unroll
        for (int ch = 0; ch < 4; ++ch) {
            int id = tid + ch * 256; int r = id >> 3, cs = id & 7;
            *(bf16x8*)&Al[r][cs * 8] = *(const bf16x8*)&A[(m0 + r) * CH + kc + cs * 8];
        }
        #pragma unroll
        for (int ch = 0; ch < 2; ++ch) {
            int id = tid + ch * 256; int r = id >> 3, cs = id & 7;
            *(bf16x8*)&Bu[r][cs * 8] = *(const bf16x8*)&Wt[(long)(n0 + r) * CH + kc + cs * 8];
            *(bf16x8*)&Bg[r][cs * 8] = *(const bf16x8*)&Wt[(long)(GLUI + n0 + r) * CH + kc + cs * 8];
        }
        __syncthreads();
        #pragma unroll
        for (int ks = 0; ks < 2; ++ks) {
            bf16x8 af[2], bu[4], bg[4];
            #pragma unroll
            for (int i = 0; i < 2; ++i) af[i] = *(const bf16x8*)&Al[wid * 32 + i * 16 + l15][ks * 32 + lg * 8];
            #pragma unroll
            for (int j = 0; j < 4; ++j) {
                bu[j] = *(const bf16x8*)&Bu[j * 16 + l15][ks * 32 + lg * 8];
                bg[j] = *(const bf16x8*)&Bg[j * 16 + l15][ks * 32 + lg * 8];
            }
            #pragma unroll
            for (int i = 0; i < 2; ++i)
                #pragma unroll
                for (int j = 0; j < 4; ++j) {
                    au[i][j] = __builtin_amdgcn_mfma_f32_16x16x32_bf16(af[i], bu[j], au[i][j], 0, 0, 0);
                    ag[i][j] = __builtin_amdgcn_mfma_f32_16x16x32_bf16(af[i], bg[j], ag[i][j], 0, 0, 0);
                }
        }
        __syncthreads();
    }
    #pragma unroll
    for (int i = 0; i < 2; ++i)
        #pragma unroll
        for (int j = 0; j < 4; ++j) {
            int col = n0 + j * 16 + l15;
            float bu_ = gb[col], bg_ = gb[col + GLUI];
            #pragma unroll
            for (int r = 0; r < 4; ++r) {
                long row = m0 + wid * 32 + i * 16 + lg * 4 + r;
                float uu = au[i][j][r] + bu_;
                float gg = ag[i][j][r] + bg_;
                float ge = 0.5f * gg * (1.f + erff(gg * 0.70710678118654752f));
                act[row * GLUI + col] = f2b(uu * ge);
            }
        }
}

// ---------------- per-window MFMA attention ---------------------------------
__global__ __launch_bounds__(256) void k_attn(const u16* __restrict__ qkvb,
                                              u16* __restrict__ obuf) {
    __shared__ u16 qk[48][392];        // rows 40..47 zero; stride 392 (16B mult)
    __shared__ u16 vT[NH][32][72];     // vT[h][d][j], j padded w/ zeros
    __shared__ u16 P[NH][48][72];      // P[h][q][key], keys 40..63 zero
    int m = blockIdx.x, tid = threadIdx.x;
    int h = tid >> 6, lane = tid & 63, l15 = lane & 15, lg = lane >> 4;

    for (int i = tid; i < (48 * 392) / 2; i += 256) ((u32*)&qk[0][0])[i] = 0;
    for (int i = tid; i < (NH * 32 * 72) / 2; i += 256) ((u32*)&vT[0][0][0])[i] = 0;
    for (int i = tid; i < (NH * 48 * 72) / 2; i += 256) ((u32*)&P[0][0][0])[i] = 0;
    __syncthreads();
    for (int i = tid; i < KA * 48; i += 256) {
        int j = i / 48, sseg = i % 48;
        *(bf16x8*)&qk[j][sseg * 8] = *(const bf16x8*)&qkvb[((long)m * KA + j) * 384 + sseg * 8];
    }
    __syncthreads();
    for (int i = tid; i < NH * 32 * KA; i += 256) {
        int hh = i / (32 * KA), rem = i % (32 * KA), d = rem / KA, j = rem % KA;
        vT[hh][d][j] = qk[j][hh * 96 + 64 + d];
    }

    // scores S = Q @ K^T (per wave = head), 3x3 tiles of 16x16, K=32
    f32x4 s[3][3];
    bf16x8 aq[3], bk[3];
    f32x4 zero = {};
    #pragma unroll
    for (int t = 0; t < 3; ++t) {
        aq[t] = *(const bf16x8*)&qk[t * 16 + l15][h * 96 + lg * 8];
        bk[t] = *(const bf16x8*)&qk[t * 16 + l15][h * 96 + 32 + lg * 8];
    }
    #pragma unroll
    for (int mi = 0; mi < 3; ++mi)
        #pragma unroll
        for (int ni = 0; ni < 3; ++ni)
            s[mi][ni] = __builtin_amdgcn_mfma_f32_16x16x32_bf16(aq[mi], bk[ni], zero, 0, 0, 0);

    const float scale = 0.17677669529663687f;
    float inv_[3][4];
    #pragma unroll
    for (int mi = 0; mi < 3; ++mi)
        #pragma unroll
        for (int r = 0; r < 4; ++r) {
            float v0 = s[mi][0][r] * scale;
            float v1 = s[mi][1][r] * scale;
            float v2 = (l15 >= 8) ? -1e30f : s[mi][2][r] * scale;   // mask keys >= 40
            float mx = fmaxf(fmaxf(v0, v1), v2);
            #pragma unroll
            for (int o = 1; o < 16; o <<= 1) mx = fmaxf(mx, __shfl_xor(mx, o));
            float e0 = __expf(v0 - mx), e1 = __expf(v1 - mx), e2 = __expf(v2 - mx);
            float sm = e0 + e1 + e2;
            #pragma unroll
            for (int o = 1; o < 16; o <<= 1) sm += __shfl_xor(sm, o);
            inv_[mi][r] = 1.f / sm;
            int row = mi * 16 + lg * 4 + r;
            P[h][row][l15]      = f2b(e0);
            P[h][row][16 + l15] = f2b(e1);
            P[h][row][32 + l15] = f2b(e2);
        }
    __syncthreads();   // vT written by all threads; P by own wave

    // O = P @ V : 3 m-tiles x 2 d-tiles, 2 k-steps (keys 0..63, zero-padded)
    f32x4 o[3][2] = {};
    #pragma unroll
    for (int ks = 0; ks < 2; ++ks) {
        bf16x8 pa[3], vb[2];
        #pragma unroll
        for (int mi = 0; mi < 3; ++mi) pa[mi] = *(const bf16x8*)&P[h][mi * 16 + l15][ks * 32 + lg * 8];
        #pragma unroll
        for (int nf = 0; nf < 2; ++nf) vb[nf] = *(const bf16x8*)&vT[h][nf * 16 + l15][ks * 32 + lg * 8];
        #pragma unroll
        for (int mi = 0; mi < 3; ++mi)
            #pragma unroll
            for (int nf = 0; nf < 2; ++nf)
                o[mi][nf] = __builtin_amdgcn_mfma_f32_16x16x32_bf16(pa[mi], vb[nf], o[mi][nf], 0, 0, 0);
    }
    #pragma unroll
    for (int mi = 0; mi < 3; ++mi)
        #pragma unroll
        for (int nf = 0; nf < 2; ++nf)
            #pragma unroll
            for (int r = 0; r < 4; ++r) {
                int row4 = mi * 16 + lg * 4 + r;
                if (row4 < KA)
                    obuf[((long)m * KA + row4) * CH + h * 32 + nf * 16 + l15] =
                        f2b(o[mi][nf][r] * inv_[mi][r]);
            }
}

// ---------------- chunk sums of mlp for the CB mean -------------------------
__global__ __launch_bounds__(256) void k_csum(const float* __restrict__ mlp,
                                              const int* __restrict__ iw,
                                              float* __restrict__ csum) {
    __shared__ float acc[2][8][CH];
    int tid = threadIdx.x, c = tid & 127, half = tid >> 7;
    #pragma unroll
    for (int i = 0; i < 8; ++i) acc[half][i][c] = 0.f;
    int base = blockIdx.x * 256;
    for (int r = base + half; r < base + 256; r += 2) {
        int cid = iw[r / KA] >> 8;      // window / 256
        acc[half][cid][c] += mlp[(long)r * CH + c];
    }
    __syncthreads();
    if (half == 0)
        #pragma unroll
        for (int i = 0; i < 8; ++i)
            atomicAdd(&csum[i * CH + c], acc[0][i][c] + acc[1][i][c]);
}

// ---------------- finalize + scatter ----------------------------------------
__global__ __launch_bounds__(256) void k_final(const float* __restrict__ r1,
                                               const float* __restrict__ mlp,
                                               const float* __restrict__ csum,
                                               const float* __restrict__ ls2,
                                               const int* __restrict__ iw,
                                               const int* __restrict__ ecb,
                                               float* __restrict__ out) {
    long idx = (long)blockIdx.x * 256 + threadIdx.x;   // MSEL*KA*CH threads
    int c = (int)(idx % CH);
    long row = idx / CH;
    int m = (int)(row / KA), k = (int)(row % KA);
    int w = iw[m];
    float xa = mlp[idx];
    if (ecb[0]) xa = 0.5f * xa + (0.5f / RPC) * csum[(w >> 8) * CH + c];
    out[((long)(w * PW + k)) * CH + c] = r1[idx] + xa * ls2[c];
}

extern "C" void kernel_launch(void* const* d_in, const int* in_sizes, int n_in,
                              void* d_out, int out_size, void* d_ws, size_t ws_size,
                              hipStream_t stream) {
    const float* x      = (const float*)d_in[0];
    const float* n1g    = (const float*)d_in[1];
    const float* n1b    = (const float*)d_in[2];
    const float* n2g    = (const float*)d_in[3];
    const float* n2b    = (const float*)d_in[4];
    const float* qkv_w  = (const float*)d_in[5];
    const float* qkv_b  = (const float*)d_in[6];
    const float* proj_w = (const float*)d_in[7];
    const float* proj_b = (const float*)d_in[8];
    const float* ls1    = (const float*)d_in[9];
    const float* ls2    = (const float*)d_in[10];
    const float* glu_w  = (const float*)d_in[11];
    const float* glu_b  = (const float*)d_in[12];
    const float* out_w  = (const float*)d_in[13];
    const float* out_b  = (const float*)d_in[14];
    const int*   iw     = (const int*)d_in[15];
    const int*   ecb    = (const int*)d_in[21];
    float* out = (float*)d_out;

    char* w = (char*)d_ws;
    float* s1f  = (float*)w;                        // 61440*128*4 = 31457280 ; mlp aliases
    u16*   s1h  = (u16*)(w + 31457280);             // 15728640 ; h aliases
    u16*   qkvb = (u16*)(w + 47185920);             // 47185920 ; act aliases
    u16*   obuf = (u16*)(w + 94371840);             // 15728640
    float* r1   = (float*)(w + 110100480);          // 31457280
    u16*   wq   = (u16*)(w + 141557760);            // 384x128
    u16*   wp   = wq + 384 * 128;                   // 128x128
    u16*   wg   = wp + 128 * 128;                   // 640x128
    u16*   wo   = wg + 640 * 128;                   // 128x320
    float* csum = (float*)(w + 141557760 + 2 * (384*128 + 128*128 + 640*128 + 128*320));
    float* mlp  = s1f;
    u16*   act  = qkvb;
    u16*   hbuf = s1h;

    k_cvtT<<<(128 * 384 + 255) / 256, 256, 0, stream>>>(qkv_w, wq, 128, 384);
    k_cvtT<<<(128 * 128 + 255) / 256, 256, 0, stream>>>(proj_w, wp, 128, 128);
    k_cvtT<<<(128 * 640 + 255) / 256, 256, 0, stream>>>(glu_w, wg, 128, 640);
    k_cvtT<<<(320 * 128 + 255) / 256, 256, 0, stream>>>(out_w, wo, 320, 128);
    hipMemsetAsync(csum, 0, 8 * CH * sizeof(float), stream);

    k_ln1 <<<N_WIN * PW / 4, 256, 0, stream>>>(x, n1g, n1b, out);
    k_ln2a<<<NTOK / 4, 256, 0, stream>>>(out, n2g, n2b, iw, s1f, s1h);
    k_gemm<128, 0><<<dim3(NTOK / 128, 6), 256, 0, stream>>>(s1h, wq, qkv_b, nullptr, nullptr, nullptr, qkvb, 384);
    k_attn<<<MSEL, 256, 0, stream>>>(qkvb, obuf);
    k_gemm<128, 1><<<dim3(NTOK / 128, 2), 256, 0, stream>>>(obuf, wp, proj_b, s1f, ls1, r1, nullptr, CH);
    k_ln2b<<<NTOK / 4, 256, 0, stream>>>(r1, n2g, n2b, hbuf);
    k_gemm_glu<<<dim3(NTOK / 128, 5), 256, 0, stream>>>(hbuf, wg, glu_b, act);
    k_gemm<320, 2><<<dim3(NTOK / 128, 2), 256, 0, stream>>>(act, wo, out_b, nullptr, nullptr, mlp, nullptr, CH);
    k_csum<<<NTOK / 256, 256, 0, stream>>>(mlp, iw, csum);
    k_final<<<(long)NTOK * CH / 256, 256, 0, stream>>>(r1, mlp, csum, ls2, iw, ecb, out);
    (void)in_sizes; (void)n_in; (void)out_size; (void)ws_size;
}

// Round 3
// 233.219 us; speedup vs baseline: 15.8078x; 1.1923x over previous
//
#include <hip/hip_runtime.h>
#include <math.h>

typedef unsigned short u16;
typedef unsigned int   u32;
typedef __attribute__((ext_vector_type(8))) short bf16x8;
typedef __attribute__((ext_vector_type(4))) float f32x4;

#define N_WIN 2048
#define PW    64
#define KA    40
#define MSEL  1536
#define CH    128
#define NH    4
#define GLUI  320
#define NTOK  (MSEL*KA)          // 61440
#define RPC   16384              // rows per chunk (for CB mean)

__device__ __forceinline__ u16 f2b(float f) {
    u32 u = __float_as_uint(f);
    return (u16)((u + 0x7FFFu + ((u >> 16) & 1u)) >> 16);
}

// ---------------- all weights fp32 -> bf16 transposed, one launch -----------
// wq[n*128+k]=qkv_w[k*384+n]; wp[n*128+k]=proj_w[k*128+n];
// wg[n*128+k]=glu_w[k*640+n]; wo[n*320+k]=out_w[k*128+n]
__global__ __launch_bounds__(256) void k_cvt(const float* __restrict__ qkv_w,
                                             const float* __restrict__ proj_w,
                                             const float* __restrict__ glu_w,
                                             const float* __restrict__ out_w,
                                             u16* __restrict__ wq, u16* __restrict__ wp,
                                             u16* __restrict__ wg, u16* __restrict__ wo) {
    int idx = blockIdx.x * 256 + threadIdx.x;
    if (idx < 49152) {
        int n = idx / 128, k = idx % 128;
        wq[idx] = f2b(qkv_w[k * 384 + n]);
    } else if (idx < 65536) {
        int i = idx - 49152, n = i / 128, k = i % 128;
        wp[i] = f2b(proj_w[k * 128 + n]);
    } else if (idx < 147456) {
        int i = idx - 65536, n = i / 128, k = i % 128;
        wg[i] = f2b(glu_w[k * 640 + n]);
    } else if (idx < 188416) {
        int i = idx - 147456, n = i / 320, k = i % 320;
        wo[i] = f2b(out_w[k * 128 + n]);
    }
}

// ---------------- LN1 over all 131072 rows -> d_out -------------------------
__global__ __launch_bounds__(256) void k_ln1(const float* __restrict__ x,
                                             const float* __restrict__ g,
                                             const float* __restrict__ b,
                                             float* __restrict__ out) {
    int wave = threadIdx.x >> 6, lane = threadIdx.x & 63;
    long row = (long)blockIdx.x * 4 + wave;
    float2 v = *(const float2*)(x + row * CH + lane * 2);
    float s = v.x + v.y, s2 = v.x * v.x + v.y * v.y;
    #pragma unroll
    for (int o = 32; o; o >>= 1) { s += __shfl_xor(s, o); s2 += __shfl_xor(s2, o); }
    float mu = s * (1.f / CH), var = s2 * (1.f / CH) - mu * mu;
    float r = rsqrtf(var + 1e-5f);
    float2 o;
    o.x = (v.x - mu) * r * g[lane * 2]     + b[lane * 2];
    o.y = (v.y - mu) * r * g[lane * 2 + 1] + b[lane * 2 + 1];
    *(float2*)(out + row * CH + lane * 2) = o;
}

// ---------------- gather + LN2 -> s1 fp32 (residual) + bf16 (GEMM A) --------
__global__ __launch_bounds__(256) void k_ln2a(const float* __restrict__ ln1,
                                              const float* __restrict__ g2,
                                              const float* __restrict__ b2,
                                              const int* __restrict__ iw,
                                              float* __restrict__ s1f,
                                              u16* __restrict__ s1h) {
    int wave = threadIdx.x >> 6, lane = threadIdx.x & 63;
    long row = (long)blockIdx.x * 4 + wave;          // < 61440
    int m = (int)(row / KA), r = (int)(row % KA);
    const float* src = ln1 + ((long)iw[m] * PW + r) * CH;
    float2 v = *(const float2*)(src + lane * 2);
    float s = v.x + v.y, s2 = v.x * v.x + v.y * v.y;
    #pragma unroll
    for (int o = 32; o; o >>= 1) { s += __shfl_xor(s, o); s2 += __shfl_xor(s2, o); }
    float mu = s * (1.f / CH), var = s2 * (1.f / CH) - mu * mu;
    float rr = rsqrtf(var + 1e-5f);
    float o0 = (v.x - mu) * rr * g2[lane * 2]     + b2[lane * 2];
    float o1 = (v.y - mu) * rr * g2[lane * 2 + 1] + b2[lane * 2 + 1];
    float2 of; of.x = o0; of.y = o1;
    *(float2*)(s1f + row * CH + lane * 2) = of;
    *(u32*)(s1h + row * CH + lane * 2) = (u32)f2b(o0) | ((u32)f2b(o1) << 16);
}

// ---------------- tiled MFMA GEMM: C = A @ Bt^T + bias ----------------------
// NB = n-tiles per block (BN = NB*16). EPI 0: bf16 out. EPI 2: f32 out.
template<int KT, int NB, int EPI>
__global__ __launch_bounds__(256) void k_gemm(const u16* __restrict__ A,
                                              const u16* __restrict__ Bt,
                                              const float* __restrict__ bias,
                                              float* __restrict__ outf,
                                              u16* __restrict__ outh, int ldo) {
    __shared__ u16 Al[128][72];
    __shared__ u16 Bl[NB * 16][72];
    int tid = threadIdx.x, wid = tid >> 6, lane = tid & 63;
    int l15 = lane & 15, lg = lane >> 4;
    long m0 = (long)blockIdx.x * 128;
    int n0 = blockIdx.y * NB * 16;
    f32x4 acc[2][NB] = {};
    for (int kc = 0; kc < KT; kc += 64) {
        #pragma unroll
        for (int ch = 0; ch < 4; ++ch) {
            int id = tid + ch * 256; int r = id >> 3, cs = id & 7;
            *(bf16x8*)&Al[r][cs * 8] = *(const bf16x8*)&A[(m0 + r) * KT + kc + cs * 8];
        }
        #pragma unroll
        for (int ch = 0; ch < NB / 2; ++ch) {
            int id = tid + ch * 256; int r = id >> 3, cs = id & 7;
            *(bf16x8*)&Bl[r][cs * 8] = *(const bf16x8*)&Bt[(long)(n0 + r) * KT + kc + cs * 8];
        }
        __syncthreads();
        #pragma unroll
        for (int ks = 0; ks < 2; ++ks) {
            bf16x8 af[2], bfr[NB];
            #pragma unroll
            for (int i = 0; i < 2; ++i) af[i] = *(const bf16x8*)&Al[wid * 32 + i * 16 + l15][ks * 32 + lg * 8];
            #pragma unroll
            for (int j = 0; j < NB; ++j) bfr[j] = *(const bf16x8*)&Bl[j * 16 + l15][ks * 32 + lg * 8];
            #pragma unroll
            for (int i = 0; i < 2; ++i)
                #pragma unroll
                for (int j = 0; j < NB; ++j)
                    acc[i][j] = __builtin_amdgcn_mfma_f32_16x16x32_bf16(af[i], bfr[j], acc[i][j], 0, 0, 0);
        }
        __syncthreads();
    }
    #pragma unroll
    for (int i = 0; i < 2; ++i)
        #pragma unroll
        for (int j = 0; j < NB; ++j) {
            int col = n0 + j * 16 + l15;
            float bcol = bias[col];
            #pragma unroll
            for (int r = 0; r < 4; ++r) {
                long row = m0 + wid * 32 + i * 16 + lg * 4 + r;
                float v = acc[i][j][r] + bcol;
                if (EPI == 0) outh[row * ldo + col] = f2b(v);
                else          outf[row * ldo + col] = v;
            }
        }
}

// ---------------- proj GEMM (BN=128) + residual + fused LN2 epilogue --------
// r1 = s1f + (o @ wp^T + pb) * ls1 ;  hbuf = bf16(LN2(r1))
__global__ __launch_bounds__(256) void k_proj(const u16* __restrict__ A,
                                              const u16* __restrict__ Bt,
                                              const float* __restrict__ bias,
                                              const float* __restrict__ s1f,
                                              const float* __restrict__ ls1,
                                              const float* __restrict__ g2,
                                              const float* __restrict__ b2,
                                              float* __restrict__ r1,
                                              u16* __restrict__ hbuf) {
    __shared__ u16 Al[128][72];
    __shared__ u16 Bl[128][72];
    int tid = threadIdx.x, wid = tid >> 6, lane = tid & 63;
    int l15 = lane & 15, lg = lane >> 4;
    long m0 = (long)blockIdx.x * 128;
    f32x4 acc[2][8] = {};
    for (int kc = 0; kc < CH; kc += 64) {
        #pragma unroll
        for (int ch = 0; ch < 4; ++ch) {
            int id = tid + ch * 256; int r = id >> 3, cs = id & 7;
            *(bf16x8*)&Al[r][cs * 8] = *(const bf16x8*)&A[(m0 + r) * CH + kc + cs * 8];
            *(bf16x8*)&Bl[r][cs * 8] = *(const bf16x8*)&Bt[(long)r * CH + kc + cs * 8];
        }
        __syncthreads();
        #pragma unroll
        for (int ks = 0; ks < 2; ++ks) {
            bf16x8 af[2], bfr[8];
            #pragma unroll
            for (int i = 0; i < 2; ++i) af[i] = *(const bf16x8*)&Al[wid * 32 + i * 16 + l15][ks * 32 + lg * 8];
            #pragma unroll
            for (int j = 0; j < 8; ++j) bfr[j] = *(const bf16x8*)&Bl[j * 16 + l15][ks * 32 + lg * 8];
            #pragma unroll
            for (int i = 0; i < 2; ++i)
                #pragma unroll
                for (int j = 0; j < 8; ++j)
                    acc[i][j] = __builtin_amdgcn_mfma_f32_16x16x32_bf16(af[i], bfr[j], acc[i][j], 0, 0, 0);
        }
        __syncthreads();
    }
    #pragma unroll
    for (int i = 0; i < 2; ++i)
        #pragma unroll
        for (int r = 0; r < 4; ++r) {
            long row = m0 + wid * 32 + i * 16 + lg * 4 + r;
            float vals[8];
            float s = 0.f, s2 = 0.f;
            #pragma unroll
            for (int j = 0; j < 8; ++j) {
                int col = j * 16 + l15;
                float v = acc[i][j][r] + bias[col];
                v = s1f[row * CH + col] + v * ls1[col];
                vals[j] = v; s += v; s2 += v * v;
            }
            #pragma unroll
            for (int msk = 1; msk < 16; msk <<= 1) { s += __shfl_xor(s, msk); s2 += __shfl_xor(s2, msk); }
            float mu = s * (1.f / CH), var = s2 * (1.f / CH) - mu * mu;
            float rr = rsqrtf(var + 1e-5f);
            #pragma unroll
            for (int j = 0; j < 8; ++j) {
                int col = j * 16 + l15;
                r1[row * CH + col]   = vals[j];
                hbuf[row * CH + col] = f2b((vals[j] - mu) * rr * g2[col] + b2[col]);
            }
        }
}

// ---------------- GLU GEMM: act = (u+bu) * gelu(g+bg), dual B tiles ---------
__global__ __launch_bounds__(256) void k_gemm_glu(const u16* __restrict__ A,
                                                  const u16* __restrict__ Wt,
                                                  const float* __restrict__ gb,
                                                  u16* __restrict__ act) {
    __shared__ u16 Al[128][72];
    __shared__ u16 Bu[64][72];
    __shared__ u16 Bg[64][72];
    int tid = threadIdx.x, wid = tid >> 6, lane = tid & 63;
    int l15 = lane & 15, lg = lane >> 4;
    long m0 = (long)blockIdx.x * 128;
    int n0 = blockIdx.y * 64;
    f32x4 au[2][4] = {}, ag[2][4] = {};
    for (int kc = 0; kc < CH; kc += 64) {
        #pragma unroll
        for (int ch = 0; ch < 4; ++ch) {
            int id = tid + ch * 256; int r = id >> 3, cs = id & 7;
            *(bf16x8*)&Al[r][cs * 8] = *(const bf16x8*)&A[(m0 + r) * CH + kc + cs * 8];
        }
        #pragma unroll
        for (int ch = 0; ch < 2; ++ch) {
            int id = tid + ch * 256; int r = id >> 3, cs = id & 7;
            *(bf16x8*)&Bu[r][cs * 8] = *(const bf16x8*)&Wt[(long)(n0 + r) * CH + kc + cs * 8];
            *(bf16x8*)&Bg[r][cs * 8] = *(const bf16x8*)&Wt[(long)(GLUI + n0 + r) * CH + kc + cs * 8];
        }
        __syncthreads();
        #pragma unroll
        for (int ks = 0; ks < 2; ++ks) {
            bf16x8 af[2], bu[4], bg[4];
            #pragma unroll
            for (int i = 0; i < 2; ++i) af[i] = *(const bf16x8*)&Al[wid * 32 + i * 16 + l15][ks * 32 + lg * 8];
            #pragma unroll
            for (int j = 0; j < 4; ++j) {
                bu[j] = *(const bf16x8*)&Bu[j * 16 + l15][ks * 32 + lg * 8];
                bg[j] = *(const bf16x8*)&Bg[j * 16 + l15][ks * 32 + lg * 8];
            }
            #pragma unroll
            for (int i = 0; i < 2; ++i)
                #pragma unroll
                for (int j = 0; j < 4; ++j) {
                    au[i][j] = __builtin_amdgcn_mfma_f32_16x16x32_bf16(af[i], bu[j], au[i][j], 0, 0, 0);
                    ag[i][j] = __builtin_amdgcn_mfma_f32_16x16x32_bf16(af[i], bg[j], ag[i][j], 0, 0, 0);
                }
        }
        __syncthreads();
    }
    #pragma unroll
    for (int i = 0; i < 2; ++i)
        #pragma unroll
        for (int j = 0; j < 4; ++j) {
            int col = n0 + j * 16 + l15;
            float bu_ = gb[col], bg_ = gb[col + GLUI];
            #pragma unroll
            for (int r = 0; r < 4; ++r) {
                long row = m0 + wid * 32 + i * 16 + lg * 4 + r;
                float uu = au[i][j][r] + bu_;
                float gg = ag[i][j][r] + bg_;
                float ge = 0.5f * gg * (1.f + erff(gg * 0.70710678118654752f));
                act[row * GLUI + col] = f2b(uu * ge);
            }
        }
}

// ---------------- per-window MFMA attention (LDS-lean: 48.6 KB) -------------
// qk stages only the 40 real rows; fragment rows >39 clamp to 39 (their
// products feed only masked keys / unwritten output rows). P is stored into
// the dead Q/K columns of qk. vT's key-tail (j>=40) is zeroed so stale-finite
// P values beyond 40 keys contribute exactly 0.
__global__ __launch_bounds__(256) void k_attn(const u16* __restrict__ qkvb,
                                              u16* __restrict__ obuf) {
    __shared__ u16 qk[KA][392];        // 31.4 KB ; row = token, col = feature
    __shared__ u16 vT[NH][32][72];     // 18.4 KB ; vT[h][d][key]
    int m = blockIdx.x, tid = threadIdx.x;
    int h = tid >> 6, lane = tid & 63, l15 = lane & 15, lg = lane >> 4;

    for (int i = tid; i < KA * 48; i += 256) {
        int j = i / 48, seg = i % 48;
        *(bf16x8*)&qk[j][seg * 8] = *(const bf16x8*)&qkvb[((long)m * KA + j) * 384 + seg * 8];
    }
    __syncthreads();
    for (int i = tid; i < NH * 32 * 64; i += 256) {
        int hh = i / (32 * 64), rem = i % (32 * 64), d = rem / 64, j = rem % 64;
        vT[hh][d][j] = (j < KA) ? qk[j][hh * 96 + 64 + d] : (u16)0;
    }
    __syncthreads();

    // S = Q @ K^T (one head per wave), 3x3 tiles of 16x16, K-dim = 32
    bf16x8 aq[3], bk[3];
    #pragma unroll
    for (int t = 0; t < 3; ++t) {
        int rr = t * 16 + l15; if (rr > KA - 1) rr = KA - 1;
        aq[t] = *(const bf16x8*)&qk[rr][h * 96 + lg * 8];
        bk[t] = *(const bf16x8*)&qk[rr][h * 96 + 32 + lg * 8];
    }
    f32x4 zero = {};
    f32x4 s[3][3];
    #pragma unroll
    for (int mi = 0; mi < 3; ++mi)
        #pragma unroll
        for (int ni = 0; ni < 3; ++ni)
            s[mi][ni] = __builtin_amdgcn_mfma_f32_16x16x32_bf16(aq[mi], bk[ni], zero, 0, 0, 0);

    // softmax per query row; write P into dead Q/K columns of qk
    const float scale = 0.17677669529663687f;
    float inv_[3][4];
    #pragma unroll
    for (int mi = 0; mi < 3; ++mi)
        #pragma unroll
        for (int r = 0; r < 4; ++r) {
            float v0 = s[mi][0][r] * scale;
            float v1 = s[mi][1][r] * scale;
            float v2 = (l15 >= 8) ? -1e30f : s[mi][2][r] * scale;   // mask keys >= 40
            float mx = fmaxf(fmaxf(v0, v1), v2);
            #pragma unroll
            for (int o = 1; o < 16; o <<= 1) mx = fmaxf(mx, __shfl_xor(mx, o));
            float e0 = __expf(v0 - mx), e1 = __expf(v1 - mx), e2 = __expf(v2 - mx);
            float sm = e0 + e1 + e2;
            #pragma unroll
            for (int o = 1; o < 16; o <<= 1) sm += __shfl_xor(sm, o);
            inv_[mi][r] = 1.f / sm;
            int row = mi * 16 + lg * 4 + r;
            if (row < KA) {
                qk[row][h * 96 + l15]      = f2b(e0);
                qk[row][h * 96 + 16 + l15] = f2b(e1);
                qk[row][h * 96 + 32 + l15] = f2b(e2);
            }
        }

    // O = P @ V : 3 m-tiles x 2 d-tiles, 2 k-steps over 64 (zero-tail) keys
    f32x4 o[3][2] = {};
    #pragma unroll
    for (int ks = 0; ks < 2; ++ks) {
        bf16x8 pa[3], vb[2];
        #pragma unroll
        for (int mi = 0; mi < 3; ++mi) {
            int rp = mi * 16 + l15; if (rp > KA - 1) rp = KA - 1;
            pa[mi] = *(const bf16x8*)&qk[rp][h * 96 + ks * 32 + lg * 8];
        }
        #pragma unroll
        for (int nf = 0; nf < 2; ++nf) vb[nf] = *(const bf16x8*)&vT[h][nf * 16 + l15][ks * 32 + lg * 8];
        #pragma unroll
        for (int mi = 0; mi < 3; ++mi)
            #pragma unroll
            for (int nf = 0; nf < 2; ++nf)
                o[mi][nf] = __builtin_amdgcn_mfma_f32_16x16x32_bf16(pa[mi], vb[nf], o[mi][nf], 0, 0, 0);
    }
    #pragma unroll
    for (int mi = 0; mi < 3; ++mi)
        #pragma unroll
        for (int nf = 0; nf < 2; ++nf)
            #pragma unroll
            for (int r = 0; r < 4; ++r) {
                int row4 = mi * 16 + lg * 4 + r;
                if (row4 < KA)
                    obuf[((long)m * KA + row4) * CH + h * 32 + nf * 16 + l15] =
                        f2b(o[mi][nf][r] * inv_[mi][r]);
            }
}

// ---------------- chunk sums of mlp for the CB mean -------------------------
__global__ __launch_bounds__(256) void k_csum(const float* __restrict__ mlp,
                                              const int* __restrict__ iw,
                                              float* __restrict__ csum) {
    __shared__ float acc[2][8][CH];
    int tid = threadIdx.x, c = tid & 127, half = tid >> 7;
    #pragma unroll
    for (int i = 0; i < 8; ++i) acc[half][i][c] = 0.f;
    int base = blockIdx.x * 256;
    for (int r = base + half; r < base + 256; r += 2) {
        int cid = iw[r / KA] >> 8;      // window / 256
        acc[half][cid][c] += mlp[(long)r * CH + c];
    }
    __syncthreads();
    if (half == 0)
        #pragma unroll
        for (int i = 0; i < 8; ++i)
            atomicAdd(&csum[i * CH + c], acc[0][i][c] + acc[1][i][c]);
}

// ---------------- finalize + scatter ----------------------------------------
__global__ __launch_bounds__(256) void k_final(const float* __restrict__ r1,
                                               const float* __restrict__ mlp,
                                               const float* __restrict__ csum,
                                               const float* __restrict__ ls2,
                                               const int* __restrict__ iw,
                                               const int* __restrict__ ecb,
                                               float* __restrict__ out) {
    long idx = (long)blockIdx.x * 256 + threadIdx.x;   // MSEL*KA*CH threads
    int c = (int)(idx % CH);
    long row = idx / CH;
    int m = (int)(row / KA), k = (int)(row % KA);
    int w = iw[m];
    float xa = mlp[idx];
    if (ecb[0]) xa = 0.5f * xa + (0.5f / RPC) * csum[(w >> 8) * CH + c];
    out[((long)(w * PW + k)) * CH + c] = r1[idx] + xa * ls2[c];
}

extern "C" void kernel_launch(void* const* d_in, const int* in_sizes, int n_in,
                              void* d_out, int out_size, void* d_ws, size_t ws_size,
                              hipStream_t stream) {
    const float* x      = (const float*)d_in[0];
    const float* n1g    = (const float*)d_in[1];
    const float* n1b    = (const float*)d_in[2];
    const float* n2g    = (const float*)d_in[3];
    const float* n2b    = (const float*)d_in[4];
    const float* qkv_w  = (const float*)d_in[5];
    const float* qkv_b  = (const float*)d_in[6];
    const float* proj_w = (const float*)d_in[7];
    const float* proj_b = (const float*)d_in[8];
    const float* ls1    = (const float*)d_in[9];
    const float* ls2    = (const float*)d_in[10];
    const float* glu_w  = (const float*)d_in[11];
    const float* glu_b  = (const float*)d_in[12];
    const float* out_w  = (const float*)d_in[13];
    const float* out_b  = (const float*)d_in[14];
    const int*   iw     = (const int*)d_in[15];
    const int*   ecb    = (const int*)d_in[21];
    float* out = (float*)d_out;

    char* w = (char*)d_ws;
    float* s1f  = (float*)w;                        // 31457280 B ; mlp aliases
    u16*   s1h  = (u16*)(w + 31457280);             // 15728640 B ; hbuf aliases
    u16*   qkvb = (u16*)(w + 47185920);             // 47185920 B ; act aliases
    u16*   obuf = (u16*)(w + 94371840);             // 15728640 B
    float* r1   = (float*)(w + 110100480);          // 31457280 B
    u16*   wq   = (u16*)(w + 141557760);            // 384x128
    u16*   wp   = wq + 384 * 128;                   // 128x128
    u16*   wg   = wp + 128 * 128;                   // 640x128
    u16*   wo   = wg + 640 * 128;                   // 128x320
    float* csum = (float*)(w + 141557760 + 2 * (384*128 + 128*128 + 640*128 + 128*320));
    float* mlp  = s1f;
    u16*   act  = qkvb;
    u16*   hbuf = s1h;

    k_cvt<<<(188416 + 255) / 256, 256, 0, stream>>>(qkv_w, proj_w, glu_w, out_w, wq, wp, wg, wo);
    hipMemsetAsync(csum, 0, 8 * CH * sizeof(float), stream);

    k_ln1 <<<N_WIN * PW / 4, 256, 0, stream>>>(x, n1g, n1b, out);
    k_ln2a<<<NTOK / 4, 256, 0, stream>>>(out, n2g, n2b, iw, s1f, s1h);
    k_gemm<128, 8, 0><<<dim3(NTOK / 128, 3), 256, 0, stream>>>(s1h, wq, qkv_b, nullptr, qkvb, 384);
    k_attn<<<MSEL, 256, 0, stream>>>(qkvb, obuf);
    k_proj<<<NTOK / 128, 256, 0, stream>>>(obuf, wp, proj_b, s1f, ls1, n2g, n2b, r1, hbuf);
    k_gemm_glu<<<dim3(NTOK / 128, 5), 256, 0, stream>>>(hbuf, wg, glu_b, act);
    k_gemm<320, 8, 2><<<dim3(NTOK / 128, 1), 256, 0, stream>>>(act, wo, out_b, mlp, nullptr, CH);
    k_csum<<<NTOK / 256, 256, 0, stream>>>(mlp, iw, csum);
    k_final<<<(long)NTOK * CH / 256, 256, 0, stream>>>(r1, mlp, csum, ls2, iw, ecb, out);
    (void)in_sizes; (void)n_in; (void)out_size; (void)ws_size;
}